// Round 5
// baseline (482.260 us; speedup 1.0000x reference)
//
#include <hip/hip_runtime.h>
#include <stdint.h>
#include <math.h>

#define SS 8
#define NBLK 8192
#define DIN 512
#define DOUT 256
#define GB 4              // graph blocks per WG (32 rows)
#define BK 32             // K chunk
#define KSTEPS 16         // DIN/BK
#define VSTR 264          // anchor bf16 LDS stride
#define EPSN 1e-12f

typedef __bf16 bf16;
typedef __bf16 bf16x8 __attribute__((ext_vector_type(8)));
typedef float  f32x4  __attribute__((ext_vector_type(4)));

__device__ __forceinline__ bf16x8 cvt8(f32x4 lo, f32x4 hi) {
    bf16x8 r;
    r[0] = (bf16)lo[0]; r[1] = (bf16)lo[1]; r[2] = (bf16)lo[2]; r[3] = (bf16)lo[3];
    r[4] = (bf16)hi[0]; r[5] = (bf16)hi[1]; r[6] = (bf16)hi[2]; r[7] = (bf16)hi[3];
    return r;
}

// ---- prep ----
// WtImg: W_gcn^T in bf16, FRAGMENT order: fragment f (=cols f*16..f*16+15) of
// K-step s is a contiguous 1 KB block: WtImg[((s*16+f)*64 + l)*8 + j] =
// W_gcn[k = s*32 + (l>>4)*8 + j][n = f*16 + (l&15)].  One bf16x8 load per lane
// at lane*16B = fully-coalesced 1 KB -> 16 fully-used 64B lines.
// Wh/Wl: W_bil split into bf16 hi+lo.
__global__ void prep_kernel(const float* __restrict__ W_gcn,
                            const float* __restrict__ W_bil,
                            bf16* __restrict__ WtImg,
                            bf16* __restrict__ Wh,
                            bf16* __restrict__ Wl) {
    int idx = blockIdx.x * 256 + threadIdx.x;   // 196608 total
    if (idx < DIN * DOUT) {
        int k = idx >> 8, n = idx & 255;
        int s  = k >> 5;
        int qq = (k >> 3) & 3;
        int j  = k & 7;
        int f  = n >> 4;
        int r  = n & 15;
        int l  = qq * 16 + r;
        size_t pos = ((size_t)((s * 16 + f) * 64) + l) * 8 + j;
        WtImg[pos] = (bf16)W_gcn[idx];
    } else {
        int j = idx - DIN * DOUT;               // < 65536
        float wv = W_bil[j];
        bf16 h = (bf16)wv;
        Wh[j] = h;
        Wl[j] = (bf16)(wv - (float)h);
    }
}

// Barrier-free K-loop: 256 threads = 4 INDEPENDENT waves.
// wave w: b = w>>1 (0=pos,1=neg), rg = w&1 -> rows wg*32 + rg*16 .. +15
// (graph blocks 2rg, 2rg+1), all 256 cols. A: per-lane direct global loads
// (row r15, 64B/row coalesced), 1-step prefetch, in-reg bf16 cvt. B: contiguous
// fragment loads from WtImg, ping-pong bh[2][8], half-step pipelined.
// No LDS, no barriers, no DMA in the K-loop — each wave is a free-running
// pipelined stream; 3 waves/SIMD provide the TLP.
__global__ __launch_bounds__(256, 3) void cola_fused9(
    const float* __restrict__ pos_x, const float* __restrict__ neg_x,
    const int* __restrict__ pos_src, const int* __restrict__ pos_dst,
    const float* __restrict__ pos_w,
    const int* __restrict__ neg_src, const int* __restrict__ neg_dst,
    const float* __restrict__ neg_w,
    const bf16* __restrict__ WtImg, const bf16* __restrict__ Wh,
    const bf16* __restrict__ Wl,
    const float* __restrict__ b_gcn, const float* __restrict__ prelu_a,
    const float* __restrict__ b_bil, float* __restrict__ out)
{
    __shared__ float adjP[GB][SS][SS];                    // 1 KB
    __shared__ float adjN[GB][SS][SS];                    // 1 KB
    __shared__ float red[5 * GB];                         // ssqP|ssqA|ssqN|scoreP|scoreN
    __shared__ __align__(16) float pool_pos[GB * DOUT];   // 4 KB
    __shared__ __align__(16) float v_lds[GB * DOUT];      // 4 KB
    __shared__ __align__(16) bf16  ahs[GB * VSTR];        // 2.06 KB
    __shared__ __align__(16) bf16  als[GB * VSTR];        // 2.06 KB

    const int t    = threadIdx.x;
    const int wg   = blockIdx.x;
    const int w    = t >> 6;          // 0..3
    const int b    = w >> 1;          // 0 = pos, 1 = neg
    const int rg   = w & 1;           // row group (16 rows)
    const int lane = t & 63;
    const int q    = lane >> 4;
    const int r15  = lane & 15;
    const int row0 = wg * (GB * SS);  // 32 rows per WG

    // ---- zero adjacency + reductions ----
    { ((float*)adjP)[t] = 0.f; ((float*)adjN)[t] = 0.f; }
    if (t < 5 * GB) red[t] = 0.f;
    __syncthreads();

    // ---- build weighted adjacency (256 edges/branch per WG, 1 each) ----
    {
        int   sp = pos_src[wg * 256 + t];
        int   dp = pos_dst[wg * 256 + t];
        float wp = pos_w[wg * 256 + t];
        int   sn = neg_src[wg * 256 + t];
        int   dn = neg_dst[wg * 256 + t];
        float wn = neg_w[wg * 256 + t];
        int gl = t >> 6;
        int base = (wg * GB + gl) * SS;
        atomicAdd(&adjP[gl][dp - base][sp - base], wp);
        atomicAdd(&adjN[gl][dn - base][sn - base], wn);
    }
    __syncthreads();   // adj final before epilogues; K-loop touches no LDS

    // ================= K-loop: barrier-free per-wave stream ==================
    const float* xb = (b == 0) ? pos_x : neg_x;
    const float* aB = xb + (size_t)(row0 + rg * 16 + r15) * DIN + q * 8;
    const bf16*  bB = WtImg + (size_t)lane * 8;

    f32x4 acc[16];
#pragma unroll
    for (int j = 0; j < 16; ++j) acc[j] = (f32x4){0.f, 0.f, 0.f, 0.f};

    bf16x8 bh0[8], bh1[8];
    // prologue: A(0) + B(0, half 0)
    f32x4 alo = *(const f32x4*)(aB);
    f32x4 ahi = *(const f32x4*)(aB + 4);
#pragma unroll
    for (int f = 0; f < 8; ++f)
        bh0[f] = *(const bf16x8*)(bB + (size_t)(0 * 16 + f) * 512);

#pragma unroll
    for (int s = 0; s < KSTEPS; ++s) {
        const int s2 = (s + 1 < KSTEPS) ? s + 1 : s;   // clamped (redundant tail)
        // issue half 1 of step s
#pragma unroll
        for (int f = 0; f < 8; ++f)
            bh1[f] = *(const bf16x8*)(bB + (size_t)(s * 16 + 8 + f) * 512);
        // A prefetch for next step
        f32x4 alo2 = *(const f32x4*)(aB + s2 * 32);
        f32x4 ahi2 = *(const f32x4*)(aB + s2 * 32 + 4);

        bf16x8 af = cvt8(alo, ahi);
        // MFMA half 0 (cols 0..127)
#pragma unroll
        for (int f = 0; f < 8; ++f)
            acc[f] = __builtin_amdgcn_mfma_f32_16x16x32_bf16(af, bh0[f], acc[f], 0, 0, 0);
        // issue half 0 of step s+1
#pragma unroll
        for (int f = 0; f < 8; ++f)
            bh0[f] = *(const bf16x8*)(bB + (size_t)(s2 * 16 + f) * 512);
        // MFMA half 1 (cols 128..255)
#pragma unroll
        for (int f = 0; f < 8; ++f)
            acc[8 + f] = __builtin_amdgcn_mfma_f32_16x16x32_bf16(af, bh1[f], acc[8 + f], 0, 0, 0);

        alo = alo2; ahi = ahi2;
    }

    const float pa = *prelu_a;
    const int gl = 2 * rg + (q >> 1);   // this lane's graph block (local 0..3)

    // ================= POS epilogue (waves 0-1) ===============================
    if (b == 0) {
        float part = 0.f;
#pragma unroll
        for (int ni = 0; ni < 16; ++ni) {
            float r0, r1, r2, r3, r4, r5, r6, r7;
#pragma unroll
            for (int r = 0; r < 4; ++r) {
                float own = acc[ni][r];
                float oth = __shfl_xor(own, 16);
                float lo = ((q & 1) == 0) ? own : oth;
                float hi = ((q & 1) == 0) ? oth : own;
                if (r == 0) { r0 = lo; r4 = hi; }
                else if (r == 1) { r1 = lo; r5 = hi; }
                else if (r == 2) { r2 = lo; r6 = hi; }
                else            { r3 = lo; r7 = hi; }
            }
            int c = ni * 16 + r15;
            float bg = b_gcn[c];
            float pool = 0.f, anch = 0.f;
#pragma unroll
            for (int d = 0; d < 8; ++d) {
                const float* ar = &adjP[gl][d][0];
                float a = bg + ar[0]*r0 + ar[1]*r1 + ar[2]*r2 + ar[3]*r3
                             + ar[4]*r4 + ar[5]*r5 + ar[6]*r6 + ar[7]*r7;
                float h = (a >= 0.f) ? a : pa * a;
                if (d < 7) pool += h; else anch = h;
            }
            float pl = pool * (1.f / 7.f);
            if ((q & 1) == 0) {
                pool_pos[gl * DOUT + c] = pl;
                part += pl * pl;
            } else {
                bf16 hh = (bf16)anch;
                ahs[gl * VSTR + c] = hh;
                als[gl * VSTR + c] = (bf16)(anch - (float)hh);
                part += anch * anch;
            }
        }
        part += __shfl_xor(part, 8);
        part += __shfl_xor(part, 4);
        part += __shfl_xor(part, 2);
        part += __shfl_xor(part, 1);
        // unique (q-group, wave) per target -> plain stores
        if (r15 == 0) { if (q & 1) red[GB + gl] = part; else red[gl] = part; }
    }
    __syncthreads();

    // ===== v = W_bil . anchor (3-term bf16 split MFMA), all 4 waves ==========
    // A rows duplicate the 4 anchors: row r15 -> anchor r15&3. C row q*4+r ->
    // anchor r, identical across q -> q==0 lanes hold results.
    {
        f32x4 accv[4];
#pragma unroll
        for (int ni = 0; ni < 4; ++ni) accv[ni] = (f32x4){0.f, 0.f, 0.f, 0.f};
        const int ga = (r15 & 3) * VSTR;
#pragma unroll
        for (int ks = 0; ks < 8; ++ks) {
            bf16x8 ah_f = *(const bf16x8*)(ahs + ga + ks * 32 + q * 8);
            bf16x8 al_f = *(const bf16x8*)(als + ga + ks * 32 + q * 8);
#pragma unroll
            for (int ni = 0; ni < 4; ++ni) {
                int d = w * 64 + ni * 16 + r15;
                bf16x8 bh = *(const bf16x8*)(Wh + (size_t)d * DOUT + ks * 32 + q * 8);
                bf16x8 bl = *(const bf16x8*)(Wl + (size_t)d * DOUT + ks * 32 + q * 8);
                accv[ni] = __builtin_amdgcn_mfma_f32_16x16x32_bf16(ah_f, bh, accv[ni], 0, 0, 0);
                accv[ni] = __builtin_amdgcn_mfma_f32_16x16x32_bf16(al_f, bh, accv[ni], 0, 0, 0);
                accv[ni] = __builtin_amdgcn_mfma_f32_16x16x32_bf16(ah_f, bl, accv[ni], 0, 0, 0);
            }
        }
        float sp[4] = {0.f, 0.f, 0.f, 0.f};
        if (q == 0) {
#pragma unroll
            for (int ni = 0; ni < 4; ++ni) {
                int d = w * 64 + ni * 16 + r15;
#pragma unroll
                for (int r = 0; r < 4; ++r) {
                    v_lds[r * DOUT + d] = accv[ni][r];
                    sp[r] += accv[ni][r] * pool_pos[r * DOUT + d];
                }
            }
        }
#pragma unroll
        for (int r = 0; r < 4; ++r) {
            sp[r] += __shfl_xor(sp[r], 8);
            sp[r] += __shfl_xor(sp[r], 4);
            sp[r] += __shfl_xor(sp[r], 2);
            sp[r] += __shfl_xor(sp[r], 1);
        }
        if (q == 0 && r15 == 0) {
#pragma unroll
            for (int r = 0; r < 4; ++r) atomicAdd(&red[3 * GB + r], sp[r]);
        }
    }
    __syncthreads();

    // ================= NEG epilogue (waves 2-3) ===============================
    if (b == 1) {
        float part = 0.f;
#pragma unroll
        for (int ni = 0; ni < 16; ++ni) {
            float r0, r1, r2, r3, r4, r5, r6, r7;
#pragma unroll
            for (int r = 0; r < 4; ++r) {
                float own = acc[ni][r];
                float oth = __shfl_xor(own, 16);
                float lo = ((q & 1) == 0) ? own : oth;
                float hi = ((q & 1) == 0) ? oth : own;
                if (r == 0) { r0 = lo; r4 = hi; }
                else if (r == 1) { r1 = lo; r5 = hi; }
                else if (r == 2) { r2 = lo; r6 = hi; }
                else            { r3 = lo; r7 = hi; }
            }
            int c = ni * 16 + r15;
            float bg = b_gcn[c];
            float pool = 0.f;
#pragma unroll
            for (int d = 0; d < 7; ++d) {
                const float* ar = &adjN[gl][d][0];
                float a = bg + ar[0]*r0 + ar[1]*r1 + ar[2]*r2 + ar[3]*r3
                             + ar[4]*r4 + ar[5]*r5 + ar[6]*r6 + ar[7]*r7;
                float h = (a >= 0.f) ? a : pa * a;
                pool += h;
            }
            float pl = pool * (1.f / 7.f);
            part += ((q & 1) == 0) ? pl * v_lds[gl * DOUT + c] : pl * pl;
        }
        part += __shfl_xor(part, 8);
        part += __shfl_xor(part, 4);
        part += __shfl_xor(part, 2);
        part += __shfl_xor(part, 1);
        if (r15 == 0) { if (q & 1) red[2 * GB + gl] = part; else red[4 * GB + gl] = part; }
    }
    __syncthreads();

    // ================= finalize ===============================================
    if (t < GB) {
        float np = fmaxf(sqrtf(red[t]), EPSN);
        float na = fmaxf(sqrtf(red[GB + t]), EPSN);
        float nn = fmaxf(sqrtf(red[2 * GB + t]), EPSN);
        float bb = b_bil[0];
        out[wg * GB + t]        = red[3 * GB + t] / (np * na) + bb;
        out[NBLK + wg * GB + t] = red[4 * GB + t] / (nn * na) + bb;
    }
}

extern "C" void kernel_launch(void* const* d_in, const int* in_sizes, int n_in,
                              void* d_out, int out_size, void* d_ws, size_t ws_size,
                              hipStream_t stream) {
    const float* pos_x   = (const float*)d_in[0];
    const float* neg_x   = (const float*)d_in[1];
    const int*   pos_src = (const int*)d_in[2];
    const int*   pos_dst = (const int*)d_in[3];
    const float* pos_w   = (const float*)d_in[4];
    const int*   neg_src = (const int*)d_in[5];
    const int*   neg_dst = (const int*)d_in[6];
    const float* neg_w   = (const float*)d_in[7];
    const float* W_gcn   = (const float*)d_in[8];
    const float* b_gcn   = (const float*)d_in[9];
    const float* prelu_a = (const float*)d_in[10];
    const float* W_bil   = (const float*)d_in[11];
    const float* b_bil   = (const float*)d_in[12];
    float* outp = (float*)d_out;

    bf16* WtImg = (bf16*)d_ws;              // 256 KB (fragment order)
    bf16* Wh    = WtImg + DIN * DOUT;       // 128 KB
    bf16* Wl    = Wh + DOUT * DOUT;         // 128 KB

    prep_kernel<<<(DIN * DOUT + DOUT * DOUT) / 256, 256, 0, stream>>>(W_gcn, W_bil, WtImg, Wh, Wl);
    cola_fused9<<<NBLK / GB, 256, 0, stream>>>(
        pos_x, neg_x, pos_src, pos_dst, pos_w, neg_src, neg_dst, neg_w,
        WtImg, Wh, Wl, b_gcn, prelu_a, b_bil, outp);
}

// Round 6
// 402.318 us; speedup vs baseline: 1.1987x; 1.1987x over previous
//
#include <hip/hip_runtime.h>
#include <stdint.h>
#include <math.h>

#define SS 8
#define NBLK 8192
#define DIN 512
#define DOUT 256
#define GB 8              // graph blocks per WG (64 rows/branch)
#define BK 32             // K chunk
#define KSTEPS 16         // DIN/BK
#define VSTR 264          // anchor bf16 LDS stride
#define EPSN 1e-12f

typedef __bf16 bf16;
typedef __bf16 bf16x8 __attribute__((ext_vector_type(8)));
typedef float  f32x4  __attribute__((ext_vector_type(4)));

typedef __attribute__((address_space(3))) uint32_t       lds_u32;
typedef __attribute__((address_space(1))) const uint32_t g_u32;

__device__ __forceinline__ void dma16(const void* g, void* l) {
    // async global->LDS, 16 B per lane; LDS dest = wave-uniform base + lane*16
    __builtin_amdgcn_global_load_lds((g_u32*)g, (lds_u32*)l, 16, 0, 0);
}

__device__ __forceinline__ bf16x8 cvt8(f32x4 lo, f32x4 hi) {
    bf16x8 r;
    r[0] = (bf16)lo[0]; r[1] = (bf16)lo[1]; r[2] = (bf16)lo[2]; r[3] = (bf16)lo[3];
    r[4] = (bf16)hi[0]; r[5] = (bf16)hi[1]; r[6] = (bf16)hi[2]; r[7] = (bf16)hi[3];
    return r;
}

// ---- prep ----
// WtImg: W_gcn^T in bf16, FRAGMENT order: fragment f (=cols f*16..f*16+15) of
// K-step s is a contiguous 1 KB block: WtImg[((s*16+f)*64 + l)*8 + j] =
// W_gcn[k = s*32 + (l>>4)*8 + j][n = f*16 + (l&15)].  A linear 1 KB DMA chunk
// reproduces the exact MFMA B-fragment image in LDS.
// Wh/Wl: W_bil split into bf16 hi+lo.
__global__ void prep_kernel(const float* __restrict__ W_gcn,
                            const float* __restrict__ W_bil,
                            bf16* __restrict__ WtImg,
                            bf16* __restrict__ Wh,
                            bf16* __restrict__ Wl) {
    int idx = blockIdx.x * 256 + threadIdx.x;   // 196608 total
    if (idx < DIN * DOUT) {
        int k = idx >> 8, n = idx & 255;
        int s  = k >> 5;
        int qq = (k >> 3) & 3;
        int j  = k & 7;
        int f  = n >> 4;
        int r  = n & 15;
        int l  = qq * 16 + r;
        size_t pos = ((size_t)((s * 16 + f) * 64) + l) * 8 + j;
        WtImg[pos] = (bf16)W_gcn[idx];
    } else {
        int j = idx - DIN * DOUT;               // < 65536
        float wv = W_bil[j];
        bf16 h = (bf16)wv;
        Wh[j] = h;
        Wl[j] = (bf16)(wv - (float)h);
    }
}

// 512 threads, 8 waves: b = w>>2 (0=pos,1=neg), rg = w&3 -> rows wg*64 +
// rg*16..+15 (graph blocks 2rg, 2rg+1), ALL 256 cols. B: one K-HALF (256 cols
// x 256 k = 128 KB, fragment order) staged into LDS via global_load_lds, read
// with linear conflict-free ds_read_b128 at static offsets. A: per-lane global
// loads (coalesced 64B/row), 1-step reg prefetch. The 8 K-steps of a phase run
// with ZERO barriers — waves drift freely; only 3 barriers touch the matmul
// (post-stage0, restage, post-K). acc[16]=64 VGPR; launch_bounds(512,2) gives
// a 256-reg budget: no spill, no load serialization (round-5 failure mode).
__global__ __launch_bounds__(512, 2) void cola_fused10(
    const float* __restrict__ pos_x, const float* __restrict__ neg_x,
    const int* __restrict__ pos_src, const int* __restrict__ pos_dst,
    const float* __restrict__ pos_w,
    const int* __restrict__ neg_src, const int* __restrict__ neg_dst,
    const float* __restrict__ neg_w,
    const bf16* __restrict__ WtImg, const bf16* __restrict__ Wh,
    const bf16* __restrict__ Wl,
    const float* __restrict__ b_gcn, const float* __restrict__ prelu_a,
    const float* __restrict__ b_bil, float* __restrict__ out)
{
    __shared__ __align__(16) bf16 bufB[128 * 512];        // 128 KB: one K-half
    __shared__ float adjP[GB][SS][SS];                    // 2 KB
    __shared__ float adjN[GB][SS][SS];                    // 2 KB
    __shared__ float red[5 * GB];                         // ssqP|ssqA|ssqN|scoreP|scoreN

    // epilogue buffers aliased onto bufB (dead after K-loop + barrier)
    float* pool_pos = (float*)&bufB[0];                   // 8 KB
    float* v_lds    = pool_pos + GB * DOUT;               // 8 KB
    bf16*  ahs      = (bf16*)(v_lds + GB * DOUT);         // 4.125 KB
    bf16*  als      = ahs + GB * VSTR;                    // 4.125 KB

    const int t    = threadIdx.x;
    const int wg   = blockIdx.x;
    const int w    = t >> 6;          // 0..7
    const int b    = w >> 2;          // 0 = pos, 1 = neg
    const int rg   = w & 3;           // 16-row group
    const int lane = t & 63;
    const int q    = lane >> 4;
    const int r15  = lane & 15;
    const int row0 = wg * 64;

    // B staging: wave w loads chunks w*16..w*16+15 of the 128-chunk K-half
    auto stageB = [&](int h) {
#pragma unroll
        for (int i = 0; i < 16; ++i) {
            int c = w * 16 + i;
            dma16(WtImg + ((size_t)(h * 128 + c)) * 512 + lane * 8,
                  bufB + (size_t)c * 512);
        }
    };

    stageB(0);                        // in flight while we build adjacency

    // ---- zero adjacency + reductions ----
    if (t < GB * 64) { ((float*)adjP)[t] = 0.f; ((float*)adjN)[t] = 0.f; }
    if (t < 5 * GB) red[t] = 0.f;
    __syncthreads();

    // ---- build weighted adjacency (512 edges/branch per WG, 1 per thread) ----
    {
        int   sp = pos_src[wg * 512 + t];
        int   dp = pos_dst[wg * 512 + t];
        float wp = pos_w[wg * 512 + t];
        int   sn = neg_src[wg * 512 + t];
        int   dn = neg_dst[wg * 512 + t];
        float wn = neg_w[wg * 512 + t];
        int gl = t >> 6;
        int base = (wg * GB + gl) * SS;
        atomicAdd(&adjP[gl][dp - base][sp - base], wp);
        atomicAdd(&adjN[gl][dn - base][sn - base], wn);
    }

    // ---- A pointers + prologue (regs; drained by the next syncthreads) ----
    const float* xb = (b == 0) ? pos_x : neg_x;
    const float* aB = xb + (size_t)(row0 + rg * 16 + r15) * DIN + q * 8;

    f32x4 acc[16];
#pragma unroll
    for (int j = 0; j < 16; ++j) acc[j] = (f32x4){0.f, 0.f, 0.f, 0.f};

    f32x4 alo = *(const f32x4*)(aB);
    f32x4 ahi = *(const f32x4*)(aB + 4);

    __syncthreads();   // stage0 DMA drained (vmcnt0) + adj atomics complete

    auto kstep = [&](int s) {
        const int s2 = (s + 1 < KSTEPS) ? s + 1 : s;   // clamped tail reload
        f32x4 alo2 = *(const f32x4*)(aB + s2 * 32);
        f32x4 ahi2 = *(const f32x4*)(aB + s2 * 32 + 4);
        bf16x8 af = cvt8(alo, ahi);
        const bf16* bp = bufB + (size_t)(s & 7) * 16 * 512 + lane * 8;
#pragma unroll
        for (int f = 0; f < 16; ++f) {
            bf16x8 bfv = *(const bf16x8*)(bp + f * 512);
            acc[f] = __builtin_amdgcn_mfma_f32_16x16x32_bf16(af, bfv, acc[f], 0, 0, 0);
        }
        alo = alo2; ahi = ahi2;
    };

    // ---- phase 0: steps 0..7, barrier-free ----
#pragma unroll
    for (int s = 0; s < 8; ++s) kstep(s);
    __syncthreads();              // all half-0 reads done
    stageB(1);
    __syncthreads();              // half-1 staged (syncthreads drains DMA)
    // ---- phase 1: steps 8..15, barrier-free ----
#pragma unroll
    for (int s = 8; s < 16; ++s) kstep(s);
    __syncthreads();              // bufB reads done before epilogue alias writes

    const float pa = *prelu_a;
    const int gl = 2 * rg + (q >> 1);   // this lane's graph block (0..7)

    // ================= POS epilogue (waves 0-3) ===============================
    if (b == 0) {
        float part = 0.f;
#pragma unroll
        for (int ni = 0; ni < 16; ++ni) {
            float r0, r1, r2, r3, r4, r5, r6, r7;
#pragma unroll
            for (int r = 0; r < 4; ++r) {
                float own = acc[ni][r];
                float oth = __shfl_xor(own, 16);
                float lo = ((q & 1) == 0) ? own : oth;
                float hi = ((q & 1) == 0) ? oth : own;
                if (r == 0) { r0 = lo; r4 = hi; }
                else if (r == 1) { r1 = lo; r5 = hi; }
                else if (r == 2) { r2 = lo; r6 = hi; }
                else            { r3 = lo; r7 = hi; }
            }
            int c = ni * 16 + r15;
            float bg = b_gcn[c];
            float pool = 0.f, anch = 0.f;
#pragma unroll
            for (int d = 0; d < 8; ++d) {
                const float* ar = &adjP[gl][d][0];
                float a = bg + ar[0]*r0 + ar[1]*r1 + ar[2]*r2 + ar[3]*r3
                             + ar[4]*r4 + ar[5]*r5 + ar[6]*r6 + ar[7]*r7;
                float h = (a >= 0.f) ? a : pa * a;
                if (d < 7) pool += h; else anch = h;
            }
            float pl = pool * (1.f / 7.f);
            if ((q & 1) == 0) {
                pool_pos[gl * DOUT + c] = pl;
                part += pl * pl;
            } else {
                bf16 hh = (bf16)anch;
                ahs[gl * VSTR + c] = hh;
                als[gl * VSTR + c] = (bf16)(anch - (float)hh);
                part += anch * anch;
            }
        }
        part += __shfl_xor(part, 8);
        part += __shfl_xor(part, 4);
        part += __shfl_xor(part, 2);
        part += __shfl_xor(part, 1);
        // unique (gl, q&1) lane per target -> plain store
        if (r15 == 0) { if (q & 1) red[GB + gl] = part; else red[gl] = part; }
    }
    __syncthreads();

    // ===== v = W_bil . anchor (3-term bf16 split MFMA), all 8 waves ==========
    // A rows duplicate the 8 anchors (rows 8..15 = rows 0..7); C row g=q*4+r,
    // q<2 lanes hold the 8 blocks.
    {
        f32x4 accv[2];
        accv[0] = (f32x4){0.f, 0.f, 0.f, 0.f};
        accv[1] = (f32x4){0.f, 0.f, 0.f, 0.f};
        const int ga = (r15 & 7) * VSTR;
#pragma unroll
        for (int ks = 0; ks < 8; ++ks) {
            bf16x8 ah_f = *(const bf16x8*)(ahs + ga + ks * 32 + q * 8);
            bf16x8 al_f = *(const bf16x8*)(als + ga + ks * 32 + q * 8);
#pragma unroll
            for (int ni = 0; ni < 2; ++ni) {
                int d = w * 32 + ni * 16 + r15;
                bf16x8 bh = *(const bf16x8*)(Wh + (size_t)d * DOUT + ks * 32 + q * 8);
                bf16x8 bl = *(const bf16x8*)(Wl + (size_t)d * DOUT + ks * 32 + q * 8);
                accv[ni] = __builtin_amdgcn_mfma_f32_16x16x32_bf16(ah_f, bh, accv[ni], 0, 0, 0);
                accv[ni] = __builtin_amdgcn_mfma_f32_16x16x32_bf16(al_f, bh, accv[ni], 0, 0, 0);
                accv[ni] = __builtin_amdgcn_mfma_f32_16x16x32_bf16(ah_f, bl, accv[ni], 0, 0, 0);
            }
        }
        float sp[4] = {0.f, 0.f, 0.f, 0.f};
        if (q < 2) {
#pragma unroll
            for (int ni = 0; ni < 2; ++ni) {
                int d = w * 32 + ni * 16 + r15;
#pragma unroll
                for (int r = 0; r < 4; ++r) {
                    int g = q * 4 + r;
                    v_lds[g * DOUT + d] = accv[ni][r];
                    sp[r] += accv[ni][r] * pool_pos[g * DOUT + d];
                }
            }
        }
#pragma unroll
        for (int r = 0; r < 4; ++r) {
            sp[r] += __shfl_xor(sp[r], 8);
            sp[r] += __shfl_xor(sp[r], 4);
            sp[r] += __shfl_xor(sp[r], 2);
            sp[r] += __shfl_xor(sp[r], 1);
        }
        if (q < 2 && r15 == 0) {
#pragma unroll
            for (int r = 0; r < 4; ++r) atomicAdd(&red[3 * GB + q * 4 + r], sp[r]);
        }
    }
    __syncthreads();

    // ================= NEG epilogue (waves 4-7) ===============================
    if (b == 1) {
        float part = 0.f;
#pragma unroll
        for (int ni = 0; ni < 16; ++ni) {
            float r0, r1, r2, r3, r4, r5, r6, r7;
#pragma unroll
            for (int r = 0; r < 4; ++r) {
                float own = acc[ni][r];
                float oth = __shfl_xor(own, 16);
                float lo = ((q & 1) == 0) ? own : oth;
                float hi = ((q & 1) == 0) ? oth : own;
                if (r == 0) { r0 = lo; r4 = hi; }
                else if (r == 1) { r1 = lo; r5 = hi; }
                else if (r == 2) { r2 = lo; r6 = hi; }
                else            { r3 = lo; r7 = hi; }
            }
            int c = ni * 16 + r15;
            float bg = b_gcn[c];
            float pool = 0.f;
#pragma unroll
            for (int d = 0; d < 7; ++d) {
                const float* ar = &adjN[gl][d][0];
                float a = bg + ar[0]*r0 + ar[1]*r1 + ar[2]*r2 + ar[3]*r3
                             + ar[4]*r4 + ar[5]*r5 + ar[6]*r6 + ar[7]*r7;
                float h = (a >= 0.f) ? a : pa * a;
                pool += h;
            }
            float pl = pool * (1.f / 7.f);
            part += ((q & 1) == 0) ? pl * v_lds[gl * DOUT + c] : pl * pl;
        }
        part += __shfl_xor(part, 8);
        part += __shfl_xor(part, 4);
        part += __shfl_xor(part, 2);
        part += __shfl_xor(part, 1);
        if (r15 == 0) { if (q & 1) red[2 * GB + gl] = part; else red[4 * GB + gl] = part; }
    }
    __syncthreads();

    // ================= finalize ===============================================
    if (t < GB) {
        float np = fmaxf(sqrtf(red[t]), EPSN);
        float na = fmaxf(sqrtf(red[GB + t]), EPSN);
        float nn = fmaxf(sqrtf(red[2 * GB + t]), EPSN);
        float bb = b_bil[0];
        out[wg * GB + t]        = red[3 * GB + t] / (np * na) + bb;
        out[NBLK + wg * GB + t] = red[4 * GB + t] / (nn * na) + bb;
    }
}

extern "C" void kernel_launch(void* const* d_in, const int* in_sizes, int n_in,
                              void* d_out, int out_size, void* d_ws, size_t ws_size,
                              hipStream_t stream) {
    const float* pos_x   = (const float*)d_in[0];
    const float* neg_x   = (const float*)d_in[1];
    const int*   pos_src = (const int*)d_in[2];
    const int*   pos_dst = (const int*)d_in[3];
    const float* pos_w   = (const float*)d_in[4];
    const int*   neg_src = (const int*)d_in[5];
    const int*   neg_dst = (const int*)d_in[6];
    const float* neg_w   = (const float*)d_in[7];
    const float* W_gcn   = (const float*)d_in[8];
    const float* b_gcn   = (const float*)d_in[9];
    const float* prelu_a = (const float*)d_in[10];
    const float* W_bil   = (const float*)d_in[11];
    const float* b_bil   = (const float*)d_in[12];
    float* outp = (float*)d_out;

    bf16* WtImg = (bf16*)d_ws;              // 256 KB (fragment order)
    bf16* Wh    = WtImg + DIN * DOUT;       // 128 KB
    bf16* Wl    = Wh + DOUT * DOUT;         // 128 KB

    prep_kernel<<<(DIN * DOUT + DOUT * DOUT) / 256, 256, 0, stream>>>(W_gcn, W_bil, WtImg, Wh, Wl);
    cola_fused10<<<NBLK / GB, 512, 0, stream>>>(
        pos_x, neg_x, pos_src, pos_dst, pos_w, neg_src, neg_dst, neg_w,
        WtImg, Wh, Wl, b_gcn, prelu_a, b_bil, outp);
}